// Round 5
// baseline (657.501 us; speedup 1.0000x reference)
//
#include <hip/hip_runtime.h>
#include <hip/hip_bf16.h>

// Shapes (fixed by reference): B=32, T=2048, H=1024, U=1024.
// out = [context (32*1024)][attention_weights (32*2048)]  (fp32)
// V_b is a uniform score shift -> cancels in softmax -> unused.

#define B_DIM 32
#define T_DIM 2048
#define H_DIM 1024
#define U_DIM 1024

typedef __bf16 bf16x8 __attribute__((ext_vector_type(8)));
typedef float f32x4 __attribute__((ext_vector_type(4)));

__device__ __forceinline__ unsigned int f2bf(float f) {
    unsigned int u = __float_as_uint(f);
    return (u + 0x7FFFu + ((u >> 16) & 1u)) >> 16;   // RNE
}

__device__ __forceinline__ unsigned int cvt2(float lo, float hi) {
    unsigned int r;
    asm("v_cvt_pk_bf16_f32 %0, %1, %2" : "=v"(r) : "v"(lo), "v"(hi));
    return r;   // RNE packed pair, low half = lo
}

__device__ __forceinline__ float fast_tanh(float x) {
    x = fminf(9.f, fmaxf(-9.f, x));
    float e = __expf(2.f * x);
    return 1.f - 2.f * __frcp_rn(e + 1.f);
}

// ---------- pass 0a: Wv (first H cols of W_w rows) -> bf16, natural [u][k] ----------
__global__ void prep_wv_kernel(const float* __restrict__ W_w,
                               unsigned short* __restrict__ wv) {
    int u = blockIdx.x;            // 1024
    int tid = threadIdx.x;         // 256
    float4 x = reinterpret_cast<const float4*>(W_w + (size_t)u * 2 * H_DIM)[tid];
    uint2 p;
    p.x = f2bf(x.x) | (f2bf(x.y) << 16);
    p.y = f2bf(x.z) | (f2bf(x.w) << 16);
    reinterpret_cast<uint2*>(wv)[(size_t)u * (H_DIM / 4) + tid] = p;
}

// ---------- pass 0b: c[b][u] = q[b] . Wq[u] + W_b[u]  (fp32 exact) ----------
__global__ void prep_c_kernel(const float* __restrict__ q,     // [B][H]
                              const float* __restrict__ W_w,   // [U][2H]
                              const float* __restrict__ W_b,   // [U]
                              float* __restrict__ cvec) {      // [B][U]
    __shared__ float4 q_sh[4][H_DIM / 4];     // 16 KB
    int bg = blockIdx.y;           // batch group: batches bg*4 .. bg*4+3
    int u0 = blockIdx.x * 64;
    int tid = threadIdx.x;
    int lane = tid & 63, w = tid >> 6;
#pragma unroll
    for (int i = 0; i < 4; i++)
        q_sh[i][tid] = reinterpret_cast<const float4*>(
            q + (size_t)(bg * 4 + i) * H_DIM)[tid];
    __syncthreads();
#pragma unroll
    for (int i = 0; i < 16; i++) {
        int u = u0 + w * 16 + i;
        const float4* wr = reinterpret_cast<const float4*>(W_w + (size_t)u * 2 * H_DIM + H_DIM);
        float s0 = 0.f, s1 = 0.f, s2 = 0.f, s3 = 0.f;
#pragma unroll
        for (int j = 0; j < 4; j++) {
            float4 wv4 = wr[j * 64 + lane];
            float4 qa = q_sh[0][j * 64 + lane];
            float4 qb = q_sh[1][j * 64 + lane];
            float4 qc = q_sh[2][j * 64 + lane];
            float4 qd = q_sh[3][j * 64 + lane];
            s0 += wv4.x * qa.x + wv4.y * qa.y + wv4.z * qa.z + wv4.w * qa.w;
            s1 += wv4.x * qb.x + wv4.y * qb.y + wv4.z * qb.z + wv4.w * qb.w;
            s2 += wv4.x * qc.x + wv4.y * qc.y + wv4.z * qc.z + wv4.w * qc.w;
            s3 += wv4.x * qd.x + wv4.y * qd.y + wv4.z * qd.z + wv4.w * qd.w;
        }
#pragma unroll
        for (int off = 32; off >= 1; off >>= 1) {
            s0 += __shfl_xor(s0, off, 64);
            s1 += __shfl_xor(s1, off, 64);
            s2 += __shfl_xor(s2, off, 64);
            s3 += __shfl_xor(s3, off, 64);
        }
        if (lane == 0) {
            float bb = W_b[u];
            cvec[(size_t)(bg * 4 + 0) * U_DIM + u] = s0 + bb;
            cvec[(size_t)(bg * 4 + 1) * U_DIM + u] = s1 + bb;
            cvec[(size_t)(bg * 4 + 2) * U_DIM + u] = s2 + bb;
            cvec[(size_t)(bg * 4 + 3) * U_DIM + u] = s3 + bb;
        }
    }
}

// ---------- pass 1: GEMM(values, Wv^T) + tanh + dot(V_w) -> partial score ----------
// 64(M) x 512(N) tile, BK=32, 256 threads = 4 waves, wave tile 64x128,
// acc[4][8]. __launch_bounds__(256,2) -> TWO INDEPENDENT blocks per CU; a
// block's barrier stalls overlap the sibling block's compute (m114 mechanism;
// every prior round ran one 512-thread lockstep block = all stalls global).
//   A: 64x32 fp32 reg-staged -> cvt_pk -> bf16 LDS (4 KB/buf, dbuf, one
//      __syncthreads per step syncing only 4 waves).
//   B: NO LDS -- each wave ping-pong prefetches its 8 B-fragments from
//      L2-resident wv straight into registers (waves own disjoint n-ranges,
//      so no duplicate traffic; removes B from the barrier path entirely).
// N split over 2 blocks -> score_part[2][B*T]. XCD-chunked block swizzle.
__global__ __launch_bounds__(256, 2)
void gemm_score_kernel(const float* __restrict__ values,        // [B*T][H]
                       const unsigned short* __restrict__ wv,   // bf16 [U][H]
                       const float* __restrict__ cvec,          // [B][U]
                       const float* __restrict__ Vw,            // [U]
                       float* __restrict__ score_part) {        // [2][B*T]
    __shared__ __align__(16) unsigned short a_sh[2][64 * 32];   // 2 x 4 KB
    __shared__ float sc_sh[64 * 4];                             // 1 KB

    const int tid = threadIdx.x;
    const int lane = tid & 63;
    const int w = tid >> 6;          // wave 0..3
    const int col = lane & 15;
    const int quad = lane >> 4;

    // XCD-chunked bijective swizzle (2048 % 8 == 0): each XCD gets a
    // contiguous 256-block chunk -> n-siblings + m-neighbors share L2.
    const int work = (blockIdx.x & 7) * 256 + (blockIdx.x >> 3);
    const int mtile = work >> 1;     // 0..1023
    const int ntile = work & 1;      // 0..1
    const int m0 = mtile * 64;
    const int b = m0 >> 11;

    f32x4 acc[4][8];
    const f32x4 zero4 = {0.f, 0.f, 0.f, 0.f};
#pragma unroll
    for (int mt = 0; mt < 4; mt++)
#pragma unroll
        for (int nt = 0; nt < 8; nt++) acc[mt][nt] = zero4;

    // A staging: thread -> row = tid>>2 (64 rows), kq = tid&3 (8 floats each)
    const int arow = tid >> 2;
    const int akq = tid & 3;
    const float4* agl = reinterpret_cast<const float4*>(
                            values + (size_t)(m0 + arow) * H_DIM) + akq * 2;
    unsigned short* adst0 = &a_sh[0][arow * 32 + akq * 8];
    unsigned short* adst1 = &a_sh[1][arow * 32 + akq * 8];

    // B: wave w owns n-range ntile*512 + w*128 (8 frags of 16)
    const char* bbase = (const char*)wv +
        (size_t)(ntile * 512 + w * 128 + col) * 2048 + quad * 16;

    bf16x8 bA[8], bB[8];
    // prologue: stage A(0) into buf0; load B(0) into bA
    {
        float4 f0 = agl[0], f1 = agl[1];
        uint4 pk;
        pk.x = cvt2(f0.x, f0.y); pk.y = cvt2(f0.z, f0.w);
        pk.z = cvt2(f1.x, f1.y); pk.w = cvt2(f1.z, f1.w);
        *reinterpret_cast<uint4*>(adst0) = pk;
#pragma unroll
        for (int nt = 0; nt < 8; nt++)
            bA[nt] = *reinterpret_cast<const bf16x8*>(bbase + (size_t)nt * 32768);
    }
    __syncthreads();

#define GSTEP(CUR, KS, BC, BN) do {                                            \
        float4 f0, f1;                                                         \
        if ((KS) < 31) {                                                       \
            f0 = agl[((KS) + 1) * 8];                                          \
            f1 = agl[((KS) + 1) * 8 + 1];                                      \
            _Pragma("unroll")                                                  \
            for (int nt = 0; nt < 8; nt++)                                     \
                BN[nt] = *reinterpret_cast<const bf16x8*>(                     \
                    bbase + (size_t)nt * 32768 + ((KS) + 1) * 64);             \
        }                                                                      \
        bf16x8 af[4];                                                          \
        _Pragma("unroll")                                                      \
        for (int mt = 0; mt < 4; mt++)                                         \
            af[mt] = *reinterpret_cast<const bf16x8*>(                         \
                &a_sh[CUR][(mt * 16 + col) * 32 + quad * 8]);                  \
        __builtin_amdgcn_s_setprio(1);                                         \
        _Pragma("unroll")                                                      \
        for (int nt = 0; nt < 8; nt++)                                         \
            _Pragma("unroll")                                                  \
            for (int mt = 0; mt < 4; mt++)                                     \
                acc[mt][nt] = __builtin_amdgcn_mfma_f32_16x16x32_bf16(         \
                    af[mt], BC[nt], acc[mt][nt], 0, 0, 0);                     \
        __builtin_amdgcn_s_setprio(0);                                         \
        if ((KS) < 31) {                                                       \
            uint4 pk;                                                          \
            pk.x = cvt2(f0.x, f0.y); pk.y = cvt2(f0.z, f0.w);                  \
            pk.z = cvt2(f1.x, f1.y); pk.w = cvt2(f1.z, f1.w);                  \
            *reinterpret_cast<uint4*>((CUR) ? adst0 : adst1) = pk;             \
        }                                                                      \
        __syncthreads();                                                       \
    } while (0)

    for (int k2 = 0; k2 < 16; k2++) {
        GSTEP(0, 2 * k2, bA, bB);
        GSTEP(1, 2 * k2 + 1, bB, bA);
    }
#undef GSTEP

    // ---- epilogue: partial score over this block's 512 u-cols ----
    float cv[8], vwv[8];
#pragma unroll
    for (int nt = 0; nt < 8; nt++) {
        int n = ntile * 512 + w * 128 + nt * 16 + col;
        cv[nt] = cvec[(size_t)b * U_DIM + n];
        vwv[nt] = Vw[n];
    }
#pragma unroll
    for (int mt = 0; mt < 4; mt++) {
#pragma unroll
        for (int j = 0; j < 4; j++) {
            float s = 0.f;
#pragma unroll
            for (int nt = 0; nt < 8; nt++)
                s += fast_tanh(acc[mt][nt][j] + cv[nt]) * vwv[nt];
            s += __shfl_xor(s, 1, 64);
            s += __shfl_xor(s, 2, 64);
            s += __shfl_xor(s, 4, 64);
            s += __shfl_xor(s, 8, 64);
            if (col == 0) sc_sh[(mt * 16 + quad * 4 + j) * 4 + w] = s;
        }
    }
    __syncthreads();
    if (tid < 64) {
        float s = sc_sh[tid * 4] + sc_sh[tid * 4 + 1] +
                  sc_sh[tid * 4 + 2] + sc_sh[tid * 4 + 3];
        score_part[(size_t)ntile * (B_DIM * T_DIM) + m0 + tid] = s;
    }
}

// ---------- pass 2: softmax over T per batch ----------
__global__ void softmax_kernel(const float* __restrict__ score_part,  // [2][B*T]
                               float* __restrict__ aw) {              // [B][T]
    int b = blockIdx.x;            // 32
    int tid = threadIdx.x;         // 256
    int lane = tid & 63, w = tid >> 6;
    __shared__ float redm[4];
    __shared__ float reds[4];
    const float* sp = score_part + (size_t)b * T_DIM;
    float loc[8];
    float m = -1e30f;
#pragma unroll
    for (int i = 0; i < 8; i++) {
        int t = tid + i * 256;
        loc[i] = sp[t] + sp[B_DIM * T_DIM + t];
        m = fmaxf(m, loc[i]);
    }
#pragma unroll
    for (int off = 32; off >= 1; off >>= 1) m = fmaxf(m, __shfl_xor(m, off, 64));
    if (lane == 0) redm[w] = m;
    __syncthreads();
    m = fmaxf(fmaxf(redm[0], redm[1]), fmaxf(redm[2], redm[3]));
    float sum = 0.f;
#pragma unroll
    for (int i = 0; i < 8; i++) {
        loc[i] = __expf(loc[i] - m);
        sum += loc[i];
    }
#pragma unroll
    for (int off = 32; off >= 1; off >>= 1) sum += __shfl_xor(sum, off, 64);
    if (lane == 0) reds[w] = sum;
    __syncthreads();
    sum = reds[0] + reds[1] + reds[2] + reds[3];
    float inv = 1.0f / sum;
#pragma unroll
    for (int i = 0; i < 8; i++)
        aw[(size_t)b * T_DIM + tid + i * 256] = loc[i] * inv;
}

// ---------- pass 3a: partial context over 64-t chunks (no atomics) ----------
__global__ void ctx_partial_kernel(const float* __restrict__ values,
                                   const float* __restrict__ aw,
                                   float* __restrict__ partial) {   // [B][32][H]
    int tc = blockIdx.x;           // 32 chunks of 64 t
    int b = blockIdx.y;            // 32
    int tid = threadIdx.x;         // 256 -> h = tid*4..+3
    __shared__ float aw_sh[64];
    if (tid < 64) aw_sh[tid] = aw[(size_t)b * T_DIM + tc * 64 + tid];
    __syncthreads();
    const float4* v4 = reinterpret_cast<const float4*>(
                           values + ((size_t)b * T_DIM + tc * 64) * H_DIM) + tid;
    float4 a = make_float4(0.f, 0.f, 0.f, 0.f);
#pragma unroll 4
    for (int t = 0; t < 64; t++) {
        float wgt = aw_sh[t];
        float4 vv = v4[(size_t)t * (H_DIM / 4)];
        a.x += wgt * vv.x; a.y += wgt * vv.y;
        a.z += wgt * vv.z; a.w += wgt * vv.w;
    }
    reinterpret_cast<float4*>(partial + ((size_t)b * 32 + tc) * H_DIM)[tid] = a;
}

// ---------- pass 3b: combine partials ----------
__global__ void ctx_combine_kernel(const float* __restrict__ partial,
                                   float* __restrict__ ctx) {
    int idx = blockIdx.x * 256 + threadIdx.x;   // 32768
    int b = idx >> 10, h = idx & (H_DIM - 1);
    float s = 0.f;
#pragma unroll
    for (int tc = 0; tc < 32; tc++)
        s += partial[((size_t)b * 32 + tc) * H_DIM + h];
    ctx[idx] = s;
}

extern "C" void kernel_launch(void* const* d_in, const int* in_sizes, int n_in,
                              void* d_out, int out_size, void* d_ws, size_t ws_size,
                              hipStream_t stream) {
    const float* query  = (const float*)d_in[0];   // [1][B][H]
    const float* values = (const float*)d_in[1];   // [B][T][H]
    const float* W_w    = (const float*)d_in[2];   // [U][2H]
    const float* W_b    = (const float*)d_in[3];   // [U]
    const float* V_w    = (const float*)d_in[4];   // [1][U]
    // d_in[5] = V_b: uniform score shift, cancels in softmax -> unused.

    float* out = (float*)d_out;
    char* ws = (char*)d_ws;
    float* cvec            = (float*)(ws);                               // 128 KB
    unsigned short* wv     = (unsigned short*)(ws + 131072);             // 2 MB
    float* score_part      = (float*)(ws + 131072 + 2097152);            // 512 KB
    float* partial         = (float*)(ws + 131072 + 2097152 + 524288);   // 4 MB
    float* ctx = out;                    // [B][H]
    float* aw  = out + B_DIM * H_DIM;    // [B][T]

    prep_wv_kernel<<<U_DIM, 256, 0, stream>>>(W_w, wv);
    prep_c_kernel<<<dim3(U_DIM / 64, B_DIM / 4), 256, 0, stream>>>(query, W_w, W_b, cvec);
    gemm_score_kernel<<<2048, 256, 0, stream>>>(values, wv, cvec, V_w, score_part);
    softmax_kernel<<<B_DIM, 256, 0, stream>>>(score_part, aw);
    ctx_partial_kernel<<<dim3(32, B_DIM), 256, 0, stream>>>(values, aw, partial);
    ctx_combine_kernel<<<128, 256, 0, stream>>>(partial, ctx);
}